// Round 20
// baseline (47.031 us; speedup 1.0000x reference)
//
#include <hip/hip_runtime.h>
#include <hip/hip_fp16.h>

typedef _Float16 half8 __attribute__((ext_vector_type(8)));
typedef float float4v __attribute__((ext_vector_type(4)));

#define E_DIM 300
#define KP 320               // padded K (10 MFMA k-steps of 32)
#define B_ 32
#define NROW_CDD 3200        // 32*5*20
#define NROW_HIS 32000       // 32*50*20
#define NCHUNK 13            // 80-col chunks (4 h each); last chunk = 40 cols (2 h)

// ---------------- Kernel 1: gather + l2-normalize -> fp16 rows (K padded to 320) --------
__global__ __launch_bounds__(256) void gather_norm(const int* __restrict__ cand,
                                                   const int* __restrict__ clk,
                                                   const float* __restrict__ emb,
                                                   _Float16* __restrict__ outH)
{
    int row  = blockIdx.x * 4 + (threadIdx.x >> 6);
    int lane = threadIdx.x & 63;
    int tok = (row < NROW_CDD) ? cand[row] : clk[row - NROW_CDD];
    const float* e = emb + (long)tok * E_DIM;
    float v[5];
    float ss = 0.f;
#pragma unroll
    for (int j = 0; j < 5; ++j) {
        int idx = lane + j * 64;
        float x = (idx < E_DIM) ? e[idx] : 0.f;
        v[j] = x;
        ss += x * x;
    }
#pragma unroll
    for (int off = 32; off; off >>= 1) ss += __shfl_xor(ss, off);
    float scale = 1.0f / fmaxf(sqrtf(ss), 1e-12f);
    _Float16* o = outH + (long)row * KP;
#pragma unroll
    for (int j = 0; j < 5; ++j) {
        int idx = lane + j * 64;
        o[idx] = (_Float16)((idx < E_DIM) ? v[j] * scale : 0.f);
    }
}

// ---------------- Kernel 2: fused hybrid GEMM + pooling, 80-col (4-h) chunks ------------
// grid (13, 32) = 416 blocks, 448 threads (7 waves), ~70.7 KB LDS -> 2 blocks/CU.
// Wave = m-tile (A rows 16w..16w+15 hoisted af[10] regs); B 80x640B staged once
// (two-phase + XOR swizzle); 50 MFMA/wave; sim -> LDS fp16; pool fused (400 thr).
__global__ __launch_bounds__(448, 2) void knrm_fused(const _Float16* __restrict__ wsH,
                                                     const float* __restrict__ cpad,
                                                     const float* __restrict__ hpad,
                                                     const float* __restrict__ ltr_w,
                                                     float* __restrict__ partial)
{
    __shared__ __align__(16) char Bbuf[80 * 640 + 128];   // 51.3 KB
    __shared__ _Float16 simT[100 * 84];                   // 16.8 KB, stride 84 (8B-aligned)
    __shared__ float hpS[80];
    __shared__ float wvS[80];
    __shared__ float cS[100];
    __shared__ float svals[400];

    int b = blockIdx.y, chunk = blockIdx.x;               // cols chunk*80..+79
    int tid = threadIdx.x;
    int wave = tid >> 6, lane = tid & 63;
    int g4 = lane >> 4, r16 = lane & 15;
    int nh = (chunk == 12) ? 2 : 4;                       // valid h's in this chunk

    const char* gA = (const char*)(wsH + (size_t)b * 100 * KP);
    const char* gB = (const char*)(wsH + (size_t)(NROW_CDD + b * 1000 + chunk * 80) * KP);
    int nrows = nh * 20;                                  // 40 or 80 valid B rows

    // ---- hoist A slice: 10 independent 16B loads (this wave's 16 rows) ----
    int rA = wave * 16 + r16; if (rA > 99) rA = 99;
    const char* pA = gA + (size_t)rA * 640;
    half8 af[10];
#pragma unroll
    for (int k = 0; k < 10; ++k) af[k] = *(const half8*)(pA + k * 64 + g4 * 16);

    // ---- stage B chunk: 80 rows x 640 B = 3200 uint4, two-phase hoisted ----
    uint4 bv[8];
#pragma unroll
    for (int j = 0; j < 8; ++j) {
        int u = tid + 448 * j; if (u > 3199) u = 3199;
        int r = u / 40;
        int rc = (r >= nrows) ? (nrows - 1) : r;          // clamp invalid rows in-bounds
        bv[j] = *(const uint4*)(gB + (size_t)(rc * 40 + (u - r * 40)) * 16);
    }
#pragma unroll
    for (int j = 0; j < 8; ++j) {
        int u = tid + 448 * j;
        if (u < 3200) {
            int r = u / 40;
            *(uint4*)(Bbuf + ((u * 16) ^ ((r & 7) << 4))) = bv[j];
        }
    }
    if (tid < 80) {
        int idx = chunk * 80 + tid;
        hpS[tid] = (idx < 1000) ? hpad[b * 1000 + idx] : 0.f;
        wvS[tid] = (idx < 1000) ? ltr_w[idx] : 0.f;
    }
    if (tid >= 128 && tid < 228) cS[tid - 128] = cpad[b * 100 + (tid - 128)];
    __syncthreads();

    // ---- GEMM: 5 n-tiles per wave, B from LDS, A from regs (50 MFMA) ----
    float4v acc[5];
#pragma unroll
    for (int n = 0; n < 5; ++n) acc[n] = (float4v){0.f, 0.f, 0.f, 0.f};

#pragma unroll
    for (int k = 0; k < 10; ++k) {
#pragma unroll
        for (int n = 0; n < 5; ++n) {
            int rB = n * 16 + r16;
            half8 bf = *(const half8*)(Bbuf + ((rB * 640 + k * 64 + g4 * 16) ^ ((rB & 7) << 4)));
            acc[n] = __builtin_amdgcn_mfma_f32_16x16x32_f16(af[k], bf, acc[n], 0, 0, 0);
        }
    }

    // C/D layout (validated r1-r19): col = lane&15 (B-row), row = (lane>>4)*4+j (A-row)
#pragma unroll
    for (int n = 0; n < 5; ++n) {
        int col = n * 16 + r16;
#pragma unroll
        for (int j = 0; j < 4; ++j) {
            int r = wave * 16 + g4 * 4 + j;
            if (r < 100) simT[r * 84 + col] = (_Float16)acc[n][j];
        }
    }
    __syncthreads();

    // ---- fused pool: thread = (hl, row); psum[20] static regs; 400 exps ----
    if (tid < 400) {
        int hl = tid / 100;              // 0..3
        int row = tid - hl * 100;        // 0..99
        if (hl < nh) {
            float psum[20];
#pragma unroll
            for (int k = 0; k < 20; ++k) psum[k] = 0.f;

            const _Float16* sp = simT + row * 84 + hl * 20;
            const float* mp = hpS + hl * 20;
#pragma unroll 4
            for (int t = 0; t < 20; ++t) {
                float s  = (float)sp[t];
                float mm = mp[t];
                float a  = -50.0f * s * s;
#pragma unroll
                for (int k = 0; k < 19; ++k) {
                    const float mu = -0.9f + 0.1f * (float)k;
                    float arg = fmaf(100.0f * mu, s, a - 50.0f * mu * mu);   // -50(s-mu)^2
                    psum[k] = fmaf(__expf(arg), mm, psum[k]);
                }
                float d = s - 1.0f;
                psum[19] = fmaf(__expf(-500000.0f * d * d), mm, psum[19]);
            }
            float val = 0.f;
            const float* wp = wvS + hl * 20;
#pragma unroll
            for (int k = 0; k < 20; ++k)
                val += __logf(fmaxf(psum[k], 1e-10f)) * wp[k];
            svals[row * 4 + hl] = val * 0.01f * cS[row];
        } else {
            svals[row * 4 + hl] = 0.f;
        }
    }
    __syncthreads();

    // ---- per-candidate partial for this chunk ----
    if (tid < 5) {
        float ssum = 0.f;
#pragma unroll
        for (int i = 0; i < 80; ++i) ssum += svals[tid * 80 + i];   // rows c*20..+19, 4 hl
        partial[(b * 5 + tid) * NCHUNK + chunk] = ssum;
    }
}

// ---------------- Kernel 3: sum chunks + bias + log_softmax over C=5 --------------------
__global__ __launch_bounds__(64) void finalize(const float* __restrict__ partial,
                                               const float* __restrict__ ltr_b,
                                               float* __restrict__ out)
{
    int b = blockIdx.x;
    int tid = threadIdx.x;
    __shared__ float sc[5];
    if (tid < 5) {
        float a = ltr_b[0];
        const float* pp = partial + (b * 5 + tid) * NCHUNK;
#pragma unroll
        for (int ch = 0; ch < NCHUNK; ++ch) a += pp[ch];
        sc[tid] = a;
    }
    __syncthreads();
    if (tid < 5) {
        float m = fmaxf(fmaxf(fmaxf(sc[0], sc[1]), fmaxf(sc[2], sc[3])), sc[4]);
        float sum = 0.f;
#pragma unroll
        for (int i = 0; i < 5; ++i) sum += __expf(sc[i] - m);
        out[b * 5 + tid] = sc[tid] - m - __logf(sum);
    }
}

extern "C" void kernel_launch(void* const* d_in, const int* in_sizes, int n_in,
                              void* d_out, int out_size, void* d_ws, size_t ws_size,
                              hipStream_t stream)
{
    const int*   cand = (const int*)d_in[0];
    const int*   clk  = (const int*)d_in[1];
    const float* cpad = (const float*)d_in[2];
    const float* hpad = (const float*)d_in[3];
    const float* emb  = (const float*)d_in[4];
    const float* lw   = (const float*)d_in[5];
    const float* lb   = (const float*)d_in[6];
    float* out = (float*)d_out;

    _Float16* wsH  = (_Float16*)d_ws;                                                // 22.528 MB
    float* partial = (float*)((char*)d_ws + (size_t)(NROW_CDD + NROW_HIS) * KP * 2); // 8.3 KB

    hipLaunchKernelGGL(gather_norm, dim3((NROW_CDD + NROW_HIS) / 4), dim3(256), 0, stream,
                       cand, clk, emb, wsH);
    hipLaunchKernelGGL(knrm_fused, dim3(NCHUNK, B_), dim3(448), 0, stream,
                       wsH, cpad, hpad, lw, partial);
    hipLaunchKernelGGL(finalize, dim3(B_), dim3(64), 0, stream, partial, lb, out);
}